// Round 7
// baseline (662.075 us; speedup 1.0000x reference)
//
#include <hip/hip_runtime.h>

#define KK 8192
#define DD 64
#define NN 16384
#define DECAYF 0.99f
#define EPSF 1e-5f
#define BATCHF 32.0f
#define CSPLIT 32
#define CODES_PER_BLK (KK / CSPLIT)       // 256 codes -> 32 KB bf16 LDS tile
#define NCT (CODES_PER_BLK / 16)          // 16 MFMA code-tiles per block
#define NSUB 4                            // 64 tokens per wave
#define XMARGIN 2.0f                      // split-qualify margin (half-score)

using short8  = __attribute__((ext_vector_type(8))) short;
using floatx4 = __attribute__((ext_vector_type(4))) float;

__device__ __forceinline__ unsigned short f2bf(float f) {  // RNE bf16
  unsigned u = __float_as_uint(f);
  return (unsigned short)((u + 0x7FFFu + ((u >> 16) & 1u)) >> 16);
}

// ---- x: fp32 -> bf16 ----
__global__ __launch_bounds__(256) void conv_kernel(const float4* __restrict__ src,
                                                   uint2* __restrict__ dst, int n4) {
  int i = blockIdx.x * 256 + threadIdx.x;
  if (i >= n4) return;
  float4 v = src[i];
  uint2 o;
  o.x = (unsigned)f2bf(v.x) | ((unsigned)f2bf(v.y) << 16);
  o.y = (unsigned)f2bf(v.z) | ((unsigned)f2bf(v.w) << 16);
  dst[i] = o;
}

// ---- codebook prep: bf16 conv + c2 + fp32 transpose, one pass ----
__global__ __launch_bounds__(256) void cbprep_kernel(const float* __restrict__ cb,
                                                     unsigned short* __restrict__ cbb,
                                                     float* __restrict__ c2,
                                                     float* __restrict__ cbT) {
  const int k = blockIdx.x * 256 + threadIdx.x;
  float4 row[16];
  const float4* rp = (const float4*)(cb + (size_t)k * DD);
  #pragma unroll
  for (int i = 0; i < 16; ++i) row[i] = rp[i];

  float s = 0.f;
  #pragma unroll
  for (int i = 0; i < 16; ++i) {
    s = fmaf(row[i].x, row[i].x, s); s = fmaf(row[i].y, row[i].y, s);
    s = fmaf(row[i].z, row[i].z, s); s = fmaf(row[i].w, row[i].w, s);
  }
  c2[k] = s;

  uint2* bp = (uint2*)(cbb + (size_t)k * DD);
  #pragma unroll
  for (int i = 0; i < 16; ++i) {
    uint2 o;
    o.x = (unsigned)f2bf(row[i].x) | ((unsigned)f2bf(row[i].y) << 16);
    o.y = (unsigned)f2bf(row[i].z) | ((unsigned)f2bf(row[i].w) << 16);
    bp[i] = o;
  }

  #pragma unroll
  for (int i = 0; i < 16; ++i) {
    cbT[(size_t)(i * 4 + 0) * KK + k] = row[i].x;
    cbT[(size_t)(i * 4 + 1) * KK + k] = row[i].y;
    cbT[(size_t)(i * 4 + 2) * KK + k] = row[i].z;
    cbT[(size_t)(i * 4 + 3) * KK + k] = row[i].w;
  }
}

// ---- pass 1: bf16 MFMA coarse half-score min per (token, split) ----
// 64 tokens/wave (NSUB=4), 256 codes/block in 32 KB swizzled LDS.
// launch_bounds(256,4): 16 waves/CU for latency hiding.
__global__ __launch_bounds__(256, 4) void pass1_kernel(const unsigned short* __restrict__ xb,
                                                       const float4* __restrict__ cbb4,
                                                       const float* __restrict__ c2,
                                                       float* __restrict__ splitmin) {
  __shared__ float4 tile[CODES_PER_BLK * 8];
  __shared__ float c2h[CODES_PER_BLK];
  const int lane = threadIdx.x & 63;
  const int wave = threadIdx.x >> 6;
  const int col = lane & 15, q = lane >> 4;
  const int tokbase = (blockIdx.x / CSPLIT) * 256 + wave * 64;
  const int split = blockIdx.x % CSPLIT;
  const int code0 = split * CODES_PER_BLK;

  {
    const int tid = threadIdx.x;
    #pragma unroll
    for (int it = 0; it < 8; ++it) {
      int C = it * 256 + tid;          // linear 16B chunk 0..2047
      int r = C >> 3, c = C & 7;
      tile[C] = cbb4[(size_t)(code0 + r) * 8 + (c ^ (r & 7))];
    }
    c2h[tid] = 0.5f * c2[code0 + tid];
  }

  short8 a[NSUB][2];
  #pragma unroll
  for (int s = 0; s < NSUB; ++s)
    #pragma unroll
    for (int kk = 0; kk < 2; ++kk)
      a[s][kk] = *(const short8*)(xb + (size_t)(tokbase + s * 16 + col) * DD + kk * 32 + q * 8);

  float mx[NSUB][4];
  #pragma unroll
  for (int s = 0; s < NSUB; ++s)
    #pragma unroll
    for (int r = 0; r < 4; ++r) mx[s][r] = -3.4e38f;

  __syncthreads();

  for (int ct = 0; ct < NCT; ++ct) {
    const int row = ct * 16 + col;
    const int rb = row * 8, rx = row & 7;
    short8 b0 = *(const short8*)&tile[rb + (q ^ rx)];
    short8 b1 = *(const short8*)&tile[rb + ((q + 4) ^ rx)];
    const float mh = -c2h[row];         // acc starts at -0.5*||c||^2
    #pragma unroll
    for (int s = 0; s < NSUB; ++s) {
      floatx4 acc = {mh, mh, mh, mh};
      acc = __builtin_amdgcn_mfma_f32_16x16x32_bf16(a[s][0], b0, acc, 0, 0, 0);
      acc = __builtin_amdgcn_mfma_f32_16x16x32_bf16(a[s][1], b1, acc, 0, 0, 0);
      #pragma unroll
      for (int r = 0; r < 4; ++r)
        mx[s][r] = fmaxf(mx[s][r], acc[r]);   // max(dot - 0.5c2) = -min half-score
    }
  }

  #pragma unroll
  for (int off = 1; off < 16; off <<= 1)
    #pragma unroll
    for (int s = 0; s < NSUB; ++s)
      #pragma unroll
      for (int r = 0; r < 4; ++r)
        mx[s][r] = fmaxf(mx[s][r], __shfl_xor(mx[s][r], off, 64));

  if (col == 0) {
    #pragma unroll
    for (int s = 0; s < NSUB; ++s)
      #pragma unroll
      for (int r = 0; r < 4; ++r) {
        const int tok = tokbase + s * 16 + q * 4 + r;
        splitmin[(size_t)tok * CSPLIT + split] = -mx[s][r];
      }
  }
}

// ---- exact pass: fp32-scan qualifying splits + write the FULL one-hot row ----
// (no memset needed for disc: every byte of each token row is written here)
__global__ __launch_bounds__(256) void exact_kernel(const float* __restrict__ x,
                                                    const float4* __restrict__ cbT4,
                                                    const float4* __restrict__ c24,
                                                    const float* __restrict__ cb,
                                                    const float* __restrict__ splitmin,
                                                    float4* __restrict__ disc4,
                                                    float* __restrict__ quant,
                                                    float* __restrict__ counts,
                                                    float* __restrict__ sums) {
  const int wv = threadIdx.x >> 6;
  const int lane = threadIdx.x & 63;
  const int tok = __builtin_amdgcn_readfirstlane(blockIdx.x * 4 + wv);
  const float4* xp = (const float4*)(x + (size_t)tok * DD);

  // gmin from splitmin (32 splits in lanes 0..31)
  float sm = (lane < CSPLIT) ? splitmin[(size_t)tok * CSPLIT + lane] : 3.4e38f;
  float gmin = sm;
  #pragma unroll
  for (int off = 32; off; off >>= 1) gmin = fminf(gmin, __shfl_xor(gmin, off, 64));
  unsigned long long mask = __ballot((lane < CSPLIT) && (sm <= gmin + XMARGIN));

  float bs = 3.4e38f;
  int bc = 0x7FFFFFFF;

  while (mask) {
    const int s = __builtin_ctzll(mask); mask &= mask - 1;   // ascending splits
    const int k4 = s * 64 + lane;        // 64 float4-groups x 4 codes = 256 codes
    float4 acc = {0.f, 0.f, 0.f, 0.f};
    #pragma unroll
    for (int db = 0; db < 4; ++db) {
      float4 xr4[4];
      #pragma unroll
      for (int j = 0; j < 4; ++j) xr4[j] = xp[db * 4 + j];   // uniform, L1-hot
      #pragma unroll
      for (int dj = 0; dj < 16; ++dj) {
        const float xd = ((const float*)xr4)[dj];
        const float4 cv = cbT4[(size_t)(db * 16 + dj) * (KK / 4) + k4];
        acc.x = fmaf(xd, cv.x, acc.x);
        acc.y = fmaf(xd, cv.y, acc.y);
        acc.z = fmaf(xd, cv.z, acc.z);
        acc.w = fmaf(xd, cv.w, acc.w);
      }
    }
    const float4 cc = c24[k4];
    const int cbase = k4 * 4;
    float sc;
    sc = fmaf(-2.f, acc.x, cc.x); if (sc < bs) { bs = sc; bc = cbase; }
    sc = fmaf(-2.f, acc.y, cc.y); if (sc < bs) { bs = sc; bc = cbase + 1; }
    sc = fmaf(-2.f, acc.z, cc.z); if (sc < bs) { bs = sc; bc = cbase + 2; }
    sc = fmaf(-2.f, acc.w, cc.w); if (sc < bs) { bs = sc; bc = cbase + 3; }
  }

  // 64-lane argmin reduce, lowest-index tie-break (matches jnp.argmin)
  #pragma unroll
  for (int off = 32; off; off >>= 1) {
    float os = __shfl_xor(bs, off, 64);
    int oc = __shfl_xor(bc, off, 64);
    if (os < bs || (os == bs && oc < bc)) { bs = os; bc = oc; }
  }

  const int code = __builtin_amdgcn_readfirstlane(bc);

  // full one-hot row: 2048 float4 per row, 32 per lane, coalesced
  {
    float4* rowp = disc4 + (size_t)tok * (KK / 4);
    #pragma unroll
    for (int j = 0; j < 32; ++j) {
      const int k0 = (j * 64 + lane) * 4;
      float4 v;
      v.x = (k0 == code) ? 1.f : 0.f;
      v.y = (k0 + 1 == code) ? 1.f : 0.f;
      v.z = (k0 + 2 == code) ? 1.f : 0.f;
      v.w = (k0 + 3 == code) ? 1.f : 0.f;
      rowp[j * 64 + lane] = v;
    }
  }

  quant[(size_t)tok * DD + lane] = cb[(size_t)code * DD + lane];
  atomicAdd(&sums[(size_t)code * DD + lane], x[(size_t)tok * DD + lane]);
  if (lane == 0) atomicAdd(&counts[code], 1.0f);
}

// ---- EMA finalize ----
__global__ __launch_bounds__(256) void finalize_kernel(
    const float* __restrict__ ema_count, const float* __restrict__ ema_weight,
    const float* __restrict__ counts, const float* __restrict__ sums,
    float* __restrict__ out_count, float* __restrict__ out_weight,
    float* __restrict__ out_cb) {
  const int e4 = blockIdx.x * 256 + threadIdx.x;
  const int k = e4 >> 4;
  float nc = ema_count[k] * DECAYF + counts[k] * (1.f - DECAYF);
  nc = (nc + EPSF) / (BATCHF + (float)KK * EPSF) * BATCHF;
  const float4 ew = ((const float4*)ema_weight)[e4];
  const float4 s  = ((const float4*)sums)[e4];
  float4 nw;
  nw.x = ew.x * DECAYF + s.x * (1.f - DECAYF);
  nw.y = ew.y * DECAYF + s.y * (1.f - DECAYF);
  nw.z = ew.z * DECAYF + s.z * (1.f - DECAYF);
  nw.w = ew.w * DECAYF + s.w * (1.f - DECAYF);
  ((float4*)out_weight)[e4] = nw;
  float4 ncb = make_float4(nw.x / nc, nw.y / nc, nw.z / nc, nw.w / nc);
  ((float4*)out_cb)[e4] = ncb;
  if ((e4 & 15) == 0) out_count[k] = nc;
}

extern "C" void kernel_launch(void* const* d_in, const int* in_sizes, int n_in,
                              void* d_out, int out_size, void* d_ws, size_t ws_size,
                              hipStream_t stream) {
  const float* x  = (const float*)d_in[0];
  const float* cb = (const float*)d_in[1];
  const float* ema_count  = (const float*)d_in[2];
  const float* ema_weight = (const float*)d_in[3];

  float* out        = (float*)d_out;
  float* disc       = out;
  float* quant      = disc + (size_t)NN * KK;
  float* out_count  = quant + (size_t)NN * DD;
  float* out_weight = out_count + KK;
  float* out_cb     = out_weight + (size_t)KK * DD;

  float* ws = (float*)d_ws;
  float*    sums     = ws;                                   // 524288 f
  float*    counts   = sums + (size_t)KK * DD;               // 8192 f
  float*    c2       = counts + KK;                          // 8192 f
  float*    splitmin = c2 + KK;                              // N*32 f (2 MB)
  unsigned short* xb  = (unsigned short*)(splitmin + (size_t)NN * CSPLIT);  // 2 MB bf16
  unsigned short* cbb = xb + (size_t)NN * DD;                // 1 MB bf16
  float*    cbT      = (float*)(cbb + (size_t)KK * DD);      // 2 MB fp32 transposed

  hipMemsetAsync(sums, 0, (size_t)(KK * DD + KK) * sizeof(float), stream); // sums+counts

  conv_kernel<<<NN * DD / 4 / 256, 256, 0, stream>>>((const float4*)x, (uint2*)xb, NN * DD / 4);
  cbprep_kernel<<<KK / 256, 256, 0, stream>>>(cb, cbb, c2, cbT);
  pass1_kernel<<<(NN / 256) * CSPLIT, 256, 0, stream>>>(xb, (const float4*)cbb, c2, splitmin);
  exact_kernel<<<NN / 4, 256, 0, stream>>>(x, (const float4*)cbT, (const float4*)c2, cb,
                                           splitmin, (float4*)disc, quant, counts, sums);
  finalize_kernel<<<KK * DD / 4 / 256, 256, 0, stream>>>(
      ema_count, ema_weight, counts, sums, out_count, out_weight, out_cb);
}